// Round 4
// baseline (190.883 us; speedup 1.0000x reference)
//
#include <hip/hip_runtime.h>
#include <math.h>

#define BB 256
#define DD 5120
#define NN 16
#define RR 160
#define CT 192          // 160 (t) + 16 (Bm) + 16 (Cm)
#define NSPLIT 32
#define K1_KRANGE 160   // 5120 / 32
#define TMP_ELEMS (BB * CT)          // 49152
#define NEGA_ELEMS (DD * NN)         // 81920

// ---------------- K1: partials[s][b][c] = x[b, ks:ks+160] @ Wcat[ks:ks+160, c]
// Zero-LDS, zero-barrier (same structure that worked for k_fused):
// thread = one c-column; W loads coalesced across lanes; x reads wave-uniform
// -> scalar path. grid (32 b-chunks FAST, 32 k-splits) = 1024 blocks x 192.
// Consecutive blocks share the same 123 KB W k-slice -> L2 hits.
__global__ __launch_bounds__(192) void k1_gemm(const float* __restrict__ x,
                                               const float* __restrict__ Wxdt,
                                               const float* __restrict__ Wbc,
                                               float* __restrict__ part) {
    const int c  = threadIdx.x;           // 0..191
    const int b0 = blockIdx.x * 8;        // fast axis: shares W slice
    const int k0 = blockIdx.y * K1_KRANGE;

    const bool isx = (c < RR);
    const float* wp = isx ? (Wxdt + (size_t)k0 * RR + c)
                          : (Wbc  + (size_t)k0 * 32 + (c - RR));
    const int wstride = isx ? RR : 32;

    float acc[8] = {};
    for (int k8 = 0; k8 < K1_KRANGE; k8 += 8) {
        float w[8];
        #pragma unroll
        for (int j = 0; j < 8; ++j) w[j] = wp[(size_t)j * wstride];
        wp += (size_t)8 * wstride;
        #pragma unroll
        for (int bi = 0; bi < 8; ++bi) {
            const float* xr = &x[(size_t)(b0 + bi) * DD + k0 + k8];  // uniform -> s_load
            const float4 ta = *(const float4*)&xr[0];
            const float4 tb = *(const float4*)&xr[4];
            acc[bi] = fmaf(ta.x, w[0], acc[bi]);
            acc[bi] = fmaf(ta.y, w[1], acc[bi]);
            acc[bi] = fmaf(ta.z, w[2], acc[bi]);
            acc[bi] = fmaf(ta.w, w[3], acc[bi]);
            acc[bi] = fmaf(tb.x, w[4], acc[bi]);
            acc[bi] = fmaf(tb.y, w[5], acc[bi]);
            acc[bi] = fmaf(tb.z, w[6], acc[bi]);
            acc[bi] = fmaf(tb.w, w[7], acc[bi]);
        }
    }

    float* p = part + (size_t)blockIdx.y * TMP_ELEMS;
    #pragma unroll
    for (int bi = 0; bi < 8; ++bi)
        p[(b0 + bi) * CT + c] = acc[bi];   // 64 consecutive c per wave: coalesced
}

// ---------------- K_RED: tmp = sum_s partials; negA = -exp(A_log) -----------
// grid: 512 blocks x 256 = 131072 = 49152 + 81920
__global__ __launch_bounds__(256) void k_red(const float* __restrict__ part,
                                             const float* __restrict__ Alog,
                                             float* __restrict__ tmp,
                                             float* __restrict__ negA) {
    const int idx = blockIdx.x * 256 + threadIdx.x;
    if (idx < TMP_ELEMS) {
        float s = 0.f;
        #pragma unroll
        for (int z = 0; z < NSPLIT; ++z) s += part[(size_t)z * TMP_ELEMS + idx];
        tmp[idx] = s;
    } else {
        const int j = idx - TMP_ELEMS;
        negA[j] = -__expf(Alog[j]);
    }
}

// ---------------- K_FUSED: dt dot-product + SSM epilogue, zero LDS/barriers -
// dt[b,d] = softplus(sum_k t[b,k]*Wdt[k,d] + bdt[d])
// y[b,d]  = sum_n (exp(negA[d,n]*dt)*h0[b,d,n] + dt*x*Bm[b,n]) * Cm[b,n] + x
// v2: h0/x/negA are PREFETCHED into registers before the dt loop so the h0
// HBM latency hides under the 160-deep dot product; dt loop holds 8
// outstanding Wdt loads. Thread owns one d x 4 b. grid (64 b FAST, 20 d).
__global__ __launch_bounds__(256) void k_fused(const float* __restrict__ x,
                                               const float* __restrict__ h0,
                                               const float* __restrict__ Wdt,
                                               const float* __restrict__ bdt,
                                               const float* __restrict__ tmp,
                                               const float* __restrict__ negA,
                                               float* __restrict__ out) {
    const int tid = threadIdx.x;
    const int b0 = blockIdx.x * 4;      // fast axis: shares Wdt panel
    const int d  = blockIdx.y * 256 + tid;

    // ---- prefetch phase: everything that doesn't depend on dt ----
    float4 h4[4][4];
    float  xe[4];
    #pragma unroll
    for (int bi = 0; bi < 4; ++bi) {
        const size_t cell = (size_t)(b0 + bi) * DD + d;
        xe[bi] = x[cell];
        const float* hp = &h0[cell * NN];
        #pragma unroll
        for (int j = 0; j < 4; ++j) h4[bi][j] = *(const float4*)&hp[j * 4];
    }
    float av[16];
    {
        const float* ap = &negA[(size_t)d * NN];
        #pragma unroll
        for (int n4 = 0; n4 < NN; n4 += 4) {
            const float4 a4 = *(const float4*)&ap[n4];
            av[n4 + 0] = a4.x; av[n4 + 1] = a4.y;
            av[n4 + 2] = a4.z; av[n4 + 3] = a4.w;
        }
    }
    const float bdv = bdt[d];

    // ---- dt dot-product: 8 outstanding Wdt loads per iteration ----
    const float* wcol = Wdt + d;
    float acc[4] = {0.f, 0.f, 0.f, 0.f};
    for (int k8 = 0; k8 < RR; k8 += 8) {
        float w[8];
        #pragma unroll
        for (int j = 0; j < 8; ++j) w[j] = wcol[(size_t)(k8 + j) * DD];
        #pragma unroll
        for (int bi = 0; bi < 4; ++bi) {
            const float* tr = &tmp[(size_t)(b0 + bi) * CT + k8];  // uniform -> s_load
            const float4 ta = *(const float4*)&tr[0];
            const float4 tb = *(const float4*)&tr[4];
            acc[bi] = fmaf(ta.x, w[0], acc[bi]);
            acc[bi] = fmaf(ta.y, w[1], acc[bi]);
            acc[bi] = fmaf(ta.z, w[2], acc[bi]);
            acc[bi] = fmaf(ta.w, w[3], acc[bi]);
            acc[bi] = fmaf(tb.x, w[4], acc[bi]);
            acc[bi] = fmaf(tb.y, w[5], acc[bi]);
            acc[bi] = fmaf(tb.z, w[6], acc[bi]);
            acc[bi] = fmaf(tb.w, w[7], acc[bi]);
        }
    }

    // ---- epilogue: softplus + SSM, consuming the prefetched registers ----
    #pragma unroll
    for (int bi = 0; bi < 4; ++bi) {
        const float z  = acc[bi] + bdv;
        const float dt = fmaxf(z, 0.f) + log1pf(__expf(-fabsf(z)));  // softplus
        const float dtx = dt * xe[bi];
        const float* bmp = &tmp[(size_t)(b0 + bi) * CT + RR];  // uniform -> s_load
        float acc4[4] = {xe[bi], 0.f, 0.f, 0.f};
        #pragma unroll
        for (int j = 0; j < 4; ++j) {
            const float hv[4] = {h4[bi][j].x, h4[bi][j].y, h4[bi][j].z, h4[bi][j].w};
            #pragma unroll
            for (int q = 0; q < 4; ++q) {
                const int n = j * 4 + q;
                const float dA = __expf(av[n] * dt);
                const float h  = fmaf(dA, hv[q], dtx * bmp[n]);
                acc4[q] = fmaf(h, bmp[16 + n], acc4[q]);
            }
        }
        out[(size_t)(b0 + bi) * DD + d] = (acc4[0] + acc4[1]) + (acc4[2] + acc4[3]);
    }
}

extern "C" void kernel_launch(void* const* d_in, const int* in_sizes, int n_in,
                              void* d_out, int out_size, void* d_ws, size_t ws_size,
                              hipStream_t stream) {
    const float* x    = (const float*)d_in[0];
    const float* h0   = (const float*)d_in[1];
    const float* Wxdt = (const float*)d_in[2];
    const float* Wdt  = (const float*)d_in[3];
    const float* bdt  = (const float*)d_in[4];
    const float* Wbc  = (const float*)d_in[5];
    const float* Alog = (const float*)d_in[6];
    float* out = (float*)d_out;

    // ws layout (floats): partials[32*49152] | tmp[49152] | negA[81920]
    float* part = (float*)d_ws;
    float* tmp  = part + (size_t)NSPLIT * TMP_ELEMS;
    float* negA = tmp + TMP_ELEMS;

    k1_gemm<<<dim3(BB / 8, NSPLIT), 192, 0, stream>>>(x, Wxdt, Wbc, part);
    k_red<<<dim3((TMP_ELEMS + NEGA_ELEMS) / 256), 256, 0, stream>>>(part, Alog, tmp, negA);
    k_fused<<<dim3(BB / 4, DD / 256), 256, 0, stream>>>(x, h0, Wdt, bdt, tmp, negA, out);
}

// Round 5
// 175.662 us; speedup vs baseline: 1.0867x; 1.0867x over previous
//
#include <hip/hip_runtime.h>
#include <math.h>

#define BB 256
#define DD 5120
#define NN 16
#define RR 160
#define CT 192          // 160 (t) + 16 (Bm) + 16 (Cm)
#define NSPLIT 32
#define TMP_ELEMS (BB * CT)          // 49152
#define NEGA_ELEMS (DD * NN)         // 81920

// ---------------- K1: partials[s][b][c] = x[b, ks:ks+160] @ Wcat[ks:ks+160, c]
// grid: (3 c-tiles, 4 b-tiles, 32 k-splits), block 256. No atomics.
// (Exact round-1 version — part of the measured-best 175 us config.)
__global__ __launch_bounds__(256) void k1_gemm(const float* __restrict__ x,
                                               const float* __restrict__ Wxdt,
                                               const float* __restrict__ Wbc,
                                               float* __restrict__ part) {
    __shared__ float xs[32][68];   // [k][b] transposed (68: b128-aligned rows)
    __shared__ float ws[32][64];   // [k][c]
    const int tid = threadIdx.x;
    const int tx = tid & 15, ty = tid >> 4;
    const int c0 = blockIdx.x * 64;
    const int b0 = blockIdx.y * 64;
    const int k0 = blockIdx.z * 160;
    float acc[4][4] = {};

    for (int kc = 0; kc < 160; kc += 32) {
        // stage x tile transposed into LDS
        {
            const int i  = tid >> 3;          // 0..31
            const int j4 = (tid & 7) * 4;     // 0..28
            #pragma unroll
            for (int rep = 0; rep < 2; ++rep) {
                const int row = i + rep * 32;
                const float4 v = *(const float4*)&x[(size_t)(b0 + row) * DD + k0 + kc + j4];
                xs[j4 + 0][row] = v.x;
                xs[j4 + 1][row] = v.y;
                xs[j4 + 2][row] = v.z;
                xs[j4 + 3][row] = v.w;
            }
        }
        // stage W tile (float4 along c; both sources are %4 aligned)
        {
            const int c4 = (tid & 15) * 4;
            const int r0 = tid >> 4;          // 0..15
            #pragma unroll
            for (int rep = 0; rep < 2; ++rep) {
                const int r  = r0 + rep * 16;
                const int kg = k0 + kc + r;
                const int cg = c0 + c4;
                float4 v;
                if (cg < RR) v = *(const float4*)&Wxdt[(size_t)kg * RR + cg];
                else         v = *(const float4*)&Wbc[(size_t)kg * 32 + (cg - RR)];
                *(float4*)&ws[r][c4] = v;
            }
        }
        __syncthreads();
        #pragma unroll
        for (int k = 0; k < 32; ++k) {
            const float4 a4 = *(const float4*)&xs[k][ty * 4];
            const float4 w4 = *(const float4*)&ws[k][tx * 4];
            const float av[4] = {a4.x, a4.y, a4.z, a4.w};
            const float wv[4] = {w4.x, w4.y, w4.z, w4.w};
            #pragma unroll
            for (int u = 0; u < 4; ++u)
                #pragma unroll
                for (int v = 0; v < 4; ++v)
                    acc[u][v] = fmaf(av[u], wv[v], acc[u][v]);
        }
        __syncthreads();
    }

    float* p = part + (size_t)blockIdx.z * TMP_ELEMS;
    #pragma unroll
    for (int u = 0; u < 4; ++u) {
        const int b = b0 + ty * 4 + u;
        *(float4*)&p[b * CT + c0 + tx * 4] =
            make_float4(acc[u][0], acc[u][1], acc[u][2], acc[u][3]);
    }
}

// ---------------- K_RED: tmp = sum_s partials; negA = -exp(A_log) -----------
// grid: 512 blocks x 256 = 131072 = 49152 + 81920
__global__ __launch_bounds__(256) void k_red(const float* __restrict__ part,
                                             const float* __restrict__ Alog,
                                             float* __restrict__ tmp,
                                             float* __restrict__ negA) {
    const int idx = blockIdx.x * 256 + threadIdx.x;
    if (idx < TMP_ELEMS) {
        float s = 0.f;
        #pragma unroll
        for (int z = 0; z < NSPLIT; ++z) s += part[(size_t)z * TMP_ELEMS + idx];
        tmp[idx] = s;
    } else {
        const int j = idx - TMP_ELEMS;
        negA[j] = -__expf(Alog[j]);
    }
}

// ---------------- K_FUSED: dt dot-product + SSM epilogue --------------------
// dt[b,d] = softplus(sum_k t[b,k]*Wdt[k,d] + bdt[d])
// y[b,d]  = sum_n (exp(negA[d,n]*dt)*h0[b,d,n] + dt*x*Bm[b,n]) * Cm[b,n] + x
// v3: t/Bm/Cm rows staged in LDS ONCE (3 KB, one barrier). Inner dt loop's
// only memory op is the coalesced Wdt load -> compiler can pipeline vmem
// across unrolled iterations with partial vmcnt waits; LDS broadcast reads
// (uniform addr, conflict-free) replace the s_load lgkmcnt(0) serializer.
// Thread owns one d x 4 b. grid (64 b-chunks FAST -> Wdt panel L2 reuse, 20 d).
__global__ __launch_bounds__(256) void k_fused(const float* __restrict__ x,
                                               const float* __restrict__ h0,
                                               const float* __restrict__ Wdt,
                                               const float* __restrict__ bdt,
                                               const float* __restrict__ tmp,
                                               const float* __restrict__ negA,
                                               float* __restrict__ out) {
    __shared__ float ts[4][CT];        // 4 rows of t(160)+Bm(16)+Cm(16)
    const int tid = threadIdx.x;
    const int b0 = blockIdx.x * 4;     // fast axis: shares Wdt panel
    const int d  = blockIdx.y * 256 + tid;

    // stage 4 t/BC rows (768 floats), coalesced, one barrier
    for (int p = tid; p < 4 * CT; p += 256)
        ts[p / CT][p % CT] = tmp[(size_t)b0 * CT + p];
    __syncthreads();

    // ---- dt dot-product: only Wdt touches vmem; t from LDS broadcast ----
    const float* wcol = Wdt + d;
    float acc[4] = {0.f, 0.f, 0.f, 0.f};
    #pragma unroll 2
    for (int k8 = 0; k8 < RR; k8 += 8) {
        float w[8];
        #pragma unroll
        for (int j = 0; j < 8; ++j) w[j] = wcol[(size_t)(k8 + j) * DD];
        #pragma unroll
        for (int bi = 0; bi < 4; ++bi) {
            const float* tr = &ts[bi][k8];
            #pragma unroll
            for (int j = 0; j < 8; ++j)
                acc[bi] = fmaf(tr[j], w[j], acc[bi]);
        }
    }

    // negA[d, 0..15] into registers (reused across the 4 b's)
    float av[16];
    {
        const float* ap = &negA[(size_t)d * NN];
        #pragma unroll
        for (int n4 = 0; n4 < NN; n4 += 4) {
            const float4 a4 = *(const float4*)&ap[n4];
            av[n4 + 0] = a4.x; av[n4 + 1] = a4.y;
            av[n4 + 2] = a4.z; av[n4 + 3] = a4.w;
        }
    }
    const float bdv = bdt[d];

    // ---- epilogue: softplus + SSM (h0 streamed here, round-3 ordering) ----
    #pragma unroll
    for (int bi = 0; bi < 4; ++bi) {
        const float z  = acc[bi] + bdv;
        const float dt = fmaxf(z, 0.f) + log1pf(__expf(-fabsf(z)));  // softplus
        const size_t cell = (size_t)(b0 + bi) * DD + d;
        const float xe  = x[cell];
        const float dtx = dt * xe;
        const float* hp = &h0[cell * NN];
        const float* bm = &ts[bi][RR];       // Bm from LDS (broadcast)
        const float* cm = &ts[bi][RR + 16];  // Cm from LDS
        float acc4[4] = {xe, 0.f, 0.f, 0.f};
        #pragma unroll
        for (int n4 = 0; n4 < NN; n4 += 4) {
            const float4 h4 = *(const float4*)&hp[n4];
            const float hv[4] = {h4.x, h4.y, h4.z, h4.w};
            #pragma unroll
            for (int q = 0; q < 4; ++q) {
                const int n = n4 + q;
                const float dA = __expf(av[n] * dt);
                const float h  = fmaf(dA, hv[q], dtx * bm[n]);
                acc4[q] = fmaf(h, cm[n], acc4[q]);
            }
        }
        out[cell] = (acc4[0] + acc4[1]) + (acc4[2] + acc4[3]);
    }
}

extern "C" void kernel_launch(void* const* d_in, const int* in_sizes, int n_in,
                              void* d_out, int out_size, void* d_ws, size_t ws_size,
                              hipStream_t stream) {
    const float* x    = (const float*)d_in[0];
    const float* h0   = (const float*)d_in[1];
    const float* Wxdt = (const float*)d_in[2];
    const float* Wdt  = (const float*)d_in[3];
    const float* bdt  = (const float*)d_in[4];
    const float* Wbc  = (const float*)d_in[5];
    const float* Alog = (const float*)d_in[6];
    float* out = (float*)d_out;

    // ws layout (floats): partials[32*49152] | tmp[49152] | negA[81920]
    float* part = (float*)d_ws;
    float* tmp  = part + (size_t)NSPLIT * TMP_ELEMS;
    float* negA = tmp + TMP_ELEMS;

    k1_gemm<<<dim3(3, 4, NSPLIT), 256, 0, stream>>>(x, Wxdt, Wbc, part);
    k_red<<<dim3((TMP_ELEMS + NEGA_ELEMS) / 256), 256, 0, stream>>>(part, Alog, tmp, negA);
    k_fused<<<dim3(BB / 4, DD / 256), 256, 0, stream>>>(x, h0, Wdt, bdt, tmp, negA, out);
}